// Round 2
// baseline (889.500 us; speedup 1.0000x reference)
//
#include <hip/hip_runtime.h>
#include <hip/hip_bf16.h>
#include <cstdint>
#include <cstddef>

#define N_NODES 50000
#define N_EDGES 800000
#define FDIM    128
#define NRBF    20
#define CUTOFF_R 5.0f
#define PI_F 3.14159265358979323846f

// ---------------------------------------------------------------------------
// Kernel 0: detect nbrs dtype. Reference says int64, but jax w/o x64 demotes
// to int32 and the harness doc says "integer -> const int*". Little-endian:
// if int64, the hi word of every value (<2^31) is 0. Random int32 src ids
// can't all be 0 over 1024 samples. flag=1 -> int64 layout, flag=0 -> int32.
// ---------------------------------------------------------------------------
__global__ void detect_kernel(const int* __restrict__ n32, int* __restrict__ flag)
{
    __shared__ int any;
    if (threadIdx.x == 0) any = 0;
    __syncthreads();
    int nz = 0;
    for (int k = threadIdx.x; k < 1024; k += 256)
        nz |= (n32[2 * k + 1] != 0) ? 1 : 0;
    if (nz) atomicOr(&any, 1);
    __syncthreads();
    if (threadIdx.x == 0) flag[0] = any ? 0 : 1;
}

// ---------------------------------------------------------------------------
// Kernel 1: PHI = silu(S @ W1 + b1) @ W2 + b2        (N x 256), fused
// Block = 256 threads, tile = 64 rows. fp32 vector FMA (no fp32 MFMA on CDNA4).
// H overwrites the S tile in place (each sS row is touched only by its own
// ty-group = intra-wave, lockstep-safe). LDS = 33KB + 8KB -> 3 blocks/CU.
// ---------------------------------------------------------------------------
__global__ __launch_bounds__(256) void node_mlp_kernel(
    const float* __restrict__ S,  const float* __restrict__ W1, const float* __restrict__ b1,
    const float* __restrict__ W2, const float* __restrict__ b2, float* __restrict__ PHI)
{
    __shared__ float sS[64][129];   // S tile, later reused as H tile
    __shared__ float sW[2048];

    const int tid  = threadIdx.x;
    const int row0 = blockIdx.x * 64;

    // stage S tile (clamp OOB rows; stores guarded later)
    for (int i = tid; i < 2048; i += 256) {
        int r  = i >> 5;
        int c4 = (i & 31) * 4;
        int gr = row0 + r; if (gr >= N_NODES) gr = N_NODES - 1;
        const float4 v = *reinterpret_cast<const float4*>(&S[(size_t)gr * FDIM + c4]);
        sS[r][c4 + 0] = v.x; sS[r][c4 + 1] = v.y; sS[r][c4 + 2] = v.z; sS[r][c4 + 3] = v.w;
    }

    const int ty = tid >> 4;   // 0..15 -> rows ty*4 .. ty*4+3
    const int tx = tid & 15;   // 0..15 -> cols tx + 16*j

    // ---- phase 1: H = silu(S@W1 + b1), 128 cols ----
    float acc1[4][8];
    #pragma unroll
    for (int i = 0; i < 4; ++i)
        #pragma unroll
        for (int j = 0; j < 8; ++j) acc1[i][j] = 0.f;

    for (int kk = 0; kk < 128; kk += 16) {
        __syncthreads();   // protects sW reuse; first iter also fences sS staging
        // stage W1 chunk [kk..kk+16) x 128
        for (int i = tid; i < 512; i += 256) {
            int r = i >> 5; int c4 = (i & 31) * 4;
            const float4 v = *reinterpret_cast<const float4*>(&W1[(size_t)(kk + r) * 128 + c4]);
            sW[r * 128 + c4 + 0] = v.x; sW[r * 128 + c4 + 1] = v.y;
            sW[r * 128 + c4 + 2] = v.z; sW[r * 128 + c4 + 3] = v.w;
        }
        __syncthreads();
        #pragma unroll
        for (int k2 = 0; k2 < 16; ++k2) {
            float a[4], b[8];
            #pragma unroll
            for (int i = 0; i < 4; ++i) a[i] = sS[ty * 4 + i][kk + k2];
            #pragma unroll
            for (int j = 0; j < 8; ++j) b[j] = sW[k2 * 128 + tx + 16 * j];
            #pragma unroll
            for (int i = 0; i < 4; ++i)
                #pragma unroll
                for (int j = 0; j < 8; ++j) acc1[i][j] = fmaf(a[i], b[j], acc1[i][j]);
        }
    }
    // write H in place of S (own rows only -> intra-wave, no barrier needed)
    #pragma unroll
    for (int i = 0; i < 4; ++i) {
        #pragma unroll
        for (int j = 0; j < 8; ++j) {
            const int c = tx + 16 * j;
            const float x = acc1[i][j] + b1[c];
            sS[ty * 4 + i][c] = x / (1.f + __expf(-x));   // silu
        }
    }

    // ---- phase 2: PHI = H@W2 + b2, 256 cols ----
    float acc2[4][16];
    #pragma unroll
    for (int i = 0; i < 4; ++i)
        #pragma unroll
        for (int j = 0; j < 16; ++j) acc2[i][j] = 0.f;

    for (int kk = 0; kk < 128; kk += 8) {
        __syncthreads();   // sW reuse fence (phase-1 readers done)
        // stage W2 chunk [kk..kk+8) x 256
        for (int i = tid; i < 512; i += 256) {
            int r = i >> 6; int c4 = (i & 63) * 4;
            const float4 v = *reinterpret_cast<const float4*>(&W2[(size_t)(kk + r) * 256 + c4]);
            sW[r * 256 + c4 + 0] = v.x; sW[r * 256 + c4 + 1] = v.y;
            sW[r * 256 + c4 + 2] = v.z; sW[r * 256 + c4 + 3] = v.w;
        }
        __syncthreads();
        #pragma unroll
        for (int k2 = 0; k2 < 8; ++k2) {
            float a[4], b[16];
            #pragma unroll
            for (int i = 0; i < 4; ++i) a[i] = sS[ty * 4 + i][kk + k2];
            #pragma unroll
            for (int j = 0; j < 16; ++j) b[j] = sW[k2 * 256 + tx + 16 * j];
            #pragma unroll
            for (int i = 0; i < 4; ++i)
                #pragma unroll
                for (int j = 0; j < 16; ++j) acc2[i][j] = fmaf(a[i], b[j], acc2[i][j]);
        }
    }
    #pragma unroll
    for (int i = 0; i < 4; ++i) {
        const int gr = row0 + ty * 4 + i;
        if (gr < N_NODES) {
            #pragma unroll
            for (int j = 0; j < 16; ++j) {
                const int c = tx + 16 * j;
                PHI[(size_t)gr * 256 + c] = acc2[i][j] + b2[c];
            }
        }
    }
}

// ---------------------------------------------------------------------------
// CSR build: histogram of dest, exclusive scan, scatter edge ids
// ---------------------------------------------------------------------------
__global__ void hist_kernel(const int* __restrict__ n32, const int* __restrict__ flag,
                            int* __restrict__ counts)
{
    const int e = blockIdx.x * blockDim.x + threadIdx.x;
    const int str = flag[0] ? 4 : 2;
    if (e < N_EDGES) {
        const int d = n32[(size_t)str * e];
        atomicAdd(&counts[d], 1);
    }
}

__global__ __launch_bounds__(1024) void scan_kernel(const int* __restrict__ counts,
                                                    int* __restrict__ offsets,
                                                    int* __restrict__ cursor)
{
    __shared__ int sums[1024];
    const int t   = threadIdx.x;
    const int per = (N_NODES + 1023) / 1024;   // 49
    const int lo  = t * per;
    const int hi  = (lo + per < N_NODES) ? lo + per : N_NODES;
    int s = 0;
    for (int i = lo; i < hi; ++i) s += counts[i];
    sums[t] = s;
    __syncthreads();
    if (t == 0) {
        int run = 0;
        for (int i = 0; i < 1024; ++i) { const int v = sums[i]; sums[i] = run; run += v; }
        offsets[N_NODES] = run;   // == N_EDGES
    }
    __syncthreads();
    int run = sums[t];
    for (int i = lo; i < hi; ++i) {
        offsets[i] = run;
        cursor[i]  = run;
        run += counts[i];
    }
}

__global__ void scatter_kernel(const int* __restrict__ n32, const int* __restrict__ flag,
                               int* __restrict__ cursor, int* __restrict__ csr)
{
    const int e = blockIdx.x * blockDim.x + threadIdx.x;
    const int str = flag[0] ? 4 : 2;
    if (e < N_EDGES) {
        const int d   = n32[(size_t)str * e];
        const int pos = atomicAdd(&cursor[d], 1);
        csr[pos] = e;
    }
}

// ---------------------------------------------------------------------------
// Kernel 5: per-node gather + edge filter + reduction. One wave per node.
// lane l owns phi channels {l, l+64} (equi) and {128+l, 192+l} (inv):
//   8 fp32 accumulators/lane, coalesced 256B gathers from PHI, single write-out.
// ---------------------------------------------------------------------------
__global__ __launch_bounds__(256) void gather_kernel(
    const float* __restrict__ PHI, const float* __restrict__ r_ij,
    const int* __restrict__ n32, const int* __restrict__ flag,
    const float* __restrict__ Wd, const float* __restrict__ bd,
    const int* __restrict__ offsets, const int* __restrict__ csr,
    float* __restrict__ out_s, float* __restrict__ out_v)
{
    __shared__ float sWd[NRBF * 256];
    __shared__ float sBd[256];

    const int tid = threadIdx.x;
    for (int i = tid; i < NRBF * 256; i += 256) sWd[i] = Wd[i];
    if (tid < 256) sBd[tid] = bd[tid];
    __syncthreads();

    const int node = blockIdx.x * 4 + (tid >> 6);
    const int l    = tid & 63;
    if (node >= N_NODES) return;

    const int f64  = flag[0];
    const int str  = f64 ? 4 : 2;
    const int soff = f64 ? 2 : 1;

    const int beg = offsets[node];
    const int end = offsets[node + 1];

    float as0 = 0.f, as1 = 0.f;
    float av0x = 0.f, av0y = 0.f, av0z = 0.f;
    float av1x = 0.f, av1y = 0.f, av1z = 0.f;

    for (int p = beg; p < end; ++p) {
        const int e = __builtin_amdgcn_readfirstlane(csr[p]);
        const int j = __builtin_amdgcn_readfirstlane(n32[(size_t)str * e + soff]);

        // issue the PHI row gather FIRST so L2/L3 latency overlaps the rbf math
        const float* ph = PHI + (size_t)j * 256;
        const float p0 = ph[l], p1 = ph[l + 64], p2 = ph[l + 128], p3 = ph[l + 192];

        const float rx = r_ij[3 * (size_t)e + 0];
        const float ry = r_ij[3 * (size_t)e + 1];
        const float rz = r_ij[3 * (size_t)e + 2];
        const float d2   = fmaf(rx, rx, fmaf(ry, ry, fmaf(rz, rz, 3e-8f)));
        const float dist = sqrtf(d2);
        if (dist >= CUTOFF_R) continue;          // env == 0, wave-uniform skip
        const float inv_d = 1.0f / dist;
        const float x  = (PI_F / CUTOFF_R) * dist;
        const float sn = __sinf(x);
        const float cn = __cosf(x);
        const float env  = 0.5f * (cn + 1.0f);
        const float twoc = 2.0f * cn;

        // w_s = rbf @ Wd + bd for this lane's 4 channels; rbf via Chebyshev:
        // sin((n+1)x) = 2cos(x) sin(nx) - sin((n-1)x)
        float w0 = sBd[l], w1 = sBd[l + 64], w2 = sBd[l + 128], w3 = sBd[l + 192];
        float sm1 = 0.f, scur = sn;
        #pragma unroll
        for (int n = 0; n < NRBF; ++n) {
            const float rb = scur * inv_d;
            w0 = fmaf(rb, sWd[n * 256 + l      ], w0);
            w1 = fmaf(rb, sWd[n * 256 + l + 64 ], w1);
            w2 = fmaf(rb, sWd[n * 256 + l + 128], w2);
            w3 = fmaf(rb, sWd[n * 256 + l + 192], w3);
            const float nxt = fmaf(twoc, scur, -sm1);
            sm1 = scur; scur = nxt;
        }

        const float ux = rx * inv_d, uy = ry * inv_d, uz = rz * inv_d;
        const float e0 = p0 * (w0 * env);
        const float e1 = p1 * (w1 * env);
        as0 = fmaf(p2, w2 * env, as0);
        as1 = fmaf(p3, w3 * env, as1);
        av0x = fmaf(e0, ux, av0x); av0y = fmaf(e0, uy, av0y); av0z = fmaf(e0, uz, av0z);
        av1x = fmaf(e1, ux, av1x); av1y = fmaf(e1, uy, av1y); av1z = fmaf(e1, uz, av1z);
    }

    // write out: delta_s (N,128), delta_v (N,128,3)
    out_s[(size_t)node * FDIM + l]      = as0;
    out_s[(size_t)node * FDIM + 64 + l] = as1;
    const size_t vb0 = ((size_t)node * FDIM + l) * 3;
    const size_t vb1 = ((size_t)node * FDIM + 64 + l) * 3;
    out_v[vb0 + 0] = av0x; out_v[vb0 + 1] = av0y; out_v[vb0 + 2] = av0z;
    out_v[vb1 + 0] = av1x; out_v[vb1 + 1] = av1y; out_v[vb1 + 2] = av1z;
}

// ---------------------------------------------------------------------------
extern "C" void kernel_launch(void* const* d_in, const int* in_sizes, int n_in,
                              void* d_out, int out_size, void* d_ws, size_t ws_size,
                              hipStream_t stream)
{
    (void)in_sizes; (void)n_in; (void)out_size; (void)ws_size;
    const float* s_j  = (const float*)d_in[0];
    // d_in[1] = v_j : UNUSED by the reference computation — never read (saves 76.8 MB)
    const float* r_ij = (const float*)d_in[2];
    const int*   n32  = (const int*)d_in[3];   // nbrs as raw 32-bit words (dtype detected)
    const float* W1   = (const float*)d_in[4];
    const float* b1   = (const float*)d_in[5];
    const float* W2   = (const float*)d_in[6];
    const float* b2   = (const float*)d_in[7];
    const float* Wd   = (const float*)d_in[8];
    const float* bd   = (const float*)d_in[9];

    float* out_s = (float*)d_out;
    float* out_v = out_s + (size_t)N_NODES * FDIM;

    // workspace layout (~55 MB)
    char*  ws      = (char*)d_ws;
    float* PHI     = (float*)(ws);                 // N*256 f32 = 51.2 MB
    int*   counts  = (int*)(ws + 51200000);        // N
    int*   offsets = (int*)(ws + 51400000);        // N+1
    int*   cursor  = (int*)(ws + 51600128);        // N
    int*   csr     = (int*)(ws + 51800128);        // E
    int*   flag    = (int*)(ws + 55000128);        // 1

    hipMemsetAsync(counts, 0, N_NODES * sizeof(int), stream);

    detect_kernel <<<1, 256, 0, stream>>>(n32, flag);
    node_mlp_kernel<<<(N_NODES + 63) / 64, 256, 0, stream>>>(s_j, W1, b1, W2, b2, PHI);
    hist_kernel   <<<(N_EDGES + 255) / 256, 256, 0, stream>>>(n32, flag, counts);
    scan_kernel   <<<1, 1024, 0, stream>>>(counts, offsets, cursor);
    scatter_kernel<<<(N_EDGES + 255) / 256, 256, 0, stream>>>(n32, flag, cursor, csr);
    gather_kernel <<<(N_NODES + 3) / 4, 256, 0, stream>>>(PHI, r_ij, n32, flag, Wd, bd,
                                                          offsets, csr, out_s, out_v);
}

// Round 3
// 715.035 us; speedup vs baseline: 1.2440x; 1.2440x over previous
//
#include <hip/hip_runtime.h>
#include <hip/hip_bf16.h>
#include <cstdint>
#include <cstddef>

#define N_NODES 50000
#define N_EDGES 800000
#define FDIM    128
#define NRBF    20
#define CUTOFF_R 5.0f
#define PI_F 3.14159265358979323846f

// ---------------------------------------------------------------------------
// Kernel 0: detect nbrs dtype (int64 vs int32 demotion). flag=1 -> int64.
// ---------------------------------------------------------------------------
__global__ void detect_kernel(const int* __restrict__ n32, int* __restrict__ flag)
{
    __shared__ int any;
    if (threadIdx.x == 0) any = 0;
    __syncthreads();
    int nz = 0;
    for (int k = threadIdx.x; k < 1024; k += 256)
        nz |= (n32[2 * k + 1] != 0) ? 1 : 0;
    if (nz) atomicOr(&any, 1);
    __syncthreads();
    if (threadIdx.x == 0) flag[0] = any ? 0 : 1;
}

// ---------------------------------------------------------------------------
// Kernel 1: PHI = silu(S @ W1 + b1) @ W2 + b2   (N x 256)  [unchanged]
// ---------------------------------------------------------------------------
__global__ __launch_bounds__(256) void node_mlp_kernel(
    const float* __restrict__ S,  const float* __restrict__ W1, const float* __restrict__ b1,
    const float* __restrict__ W2, const float* __restrict__ b2, float* __restrict__ PHI)
{
    __shared__ float sS[64][129];   // S tile, later reused as H tile
    __shared__ float sW[2048];

    const int tid  = threadIdx.x;
    const int row0 = blockIdx.x * 64;

    for (int i = tid; i < 2048; i += 256) {
        int r  = i >> 5;
        int c4 = (i & 31) * 4;
        int gr = row0 + r; if (gr >= N_NODES) gr = N_NODES - 1;
        const float4 v = *reinterpret_cast<const float4*>(&S[(size_t)gr * FDIM + c4]);
        sS[r][c4 + 0] = v.x; sS[r][c4 + 1] = v.y; sS[r][c4 + 2] = v.z; sS[r][c4 + 3] = v.w;
    }

    const int ty = tid >> 4;
    const int tx = tid & 15;

    float acc1[4][8];
    #pragma unroll
    for (int i = 0; i < 4; ++i)
        #pragma unroll
        for (int j = 0; j < 8; ++j) acc1[i][j] = 0.f;

    for (int kk = 0; kk < 128; kk += 16) {
        __syncthreads();
        for (int i = tid; i < 512; i += 256) {
            int r = i >> 5; int c4 = (i & 31) * 4;
            const float4 v = *reinterpret_cast<const float4*>(&W1[(size_t)(kk + r) * 128 + c4]);
            sW[r * 128 + c4 + 0] = v.x; sW[r * 128 + c4 + 1] = v.y;
            sW[r * 128 + c4 + 2] = v.z; sW[r * 128 + c4 + 3] = v.w;
        }
        __syncthreads();
        #pragma unroll
        for (int k2 = 0; k2 < 16; ++k2) {
            float a[4], b[8];
            #pragma unroll
            for (int i = 0; i < 4; ++i) a[i] = sS[ty * 4 + i][kk + k2];
            #pragma unroll
            for (int j = 0; j < 8; ++j) b[j] = sW[k2 * 128 + tx + 16 * j];
            #pragma unroll
            for (int i = 0; i < 4; ++i)
                #pragma unroll
                for (int j = 0; j < 8; ++j) acc1[i][j] = fmaf(a[i], b[j], acc1[i][j]);
        }
    }
    #pragma unroll
    for (int i = 0; i < 4; ++i) {
        #pragma unroll
        for (int j = 0; j < 8; ++j) {
            const int c = tx + 16 * j;
            const float x = acc1[i][j] + b1[c];
            sS[ty * 4 + i][c] = x / (1.f + __expf(-x));   // silu, in place (own rows)
        }
    }

    float acc2[4][16];
    #pragma unroll
    for (int i = 0; i < 4; ++i)
        #pragma unroll
        for (int j = 0; j < 16; ++j) acc2[i][j] = 0.f;

    for (int kk = 0; kk < 128; kk += 8) {
        __syncthreads();
        for (int i = tid; i < 512; i += 256) {
            int r = i >> 6; int c4 = (i & 63) * 4;
            const float4 v = *reinterpret_cast<const float4*>(&W2[(size_t)(kk + r) * 256 + c4]);
            sW[r * 256 + c4 + 0] = v.x; sW[r * 256 + c4 + 1] = v.y;
            sW[r * 256 + c4 + 2] = v.z; sW[r * 256 + c4 + 3] = v.w;
        }
        __syncthreads();
        #pragma unroll
        for (int k2 = 0; k2 < 8; ++k2) {
            float a[4], b[16];
            #pragma unroll
            for (int i = 0; i < 4; ++i) a[i] = sS[ty * 4 + i][kk + k2];
            #pragma unroll
            for (int j = 0; j < 16; ++j) b[j] = sW[k2 * 256 + tx + 16 * j];
            #pragma unroll
            for (int i = 0; i < 4; ++i)
                #pragma unroll
                for (int j = 0; j < 16; ++j) acc2[i][j] = fmaf(a[i], b[j], acc2[i][j]);
        }
    }
    #pragma unroll
    for (int i = 0; i < 4; ++i) {
        const int gr = row0 + ty * 4 + i;
        if (gr < N_NODES) {
            #pragma unroll
            for (int j = 0; j < 16; ++j) {
                const int c = tx + 16 * j;
                PHI[(size_t)gr * 256 + c] = acc2[i][j] + b2[c];
            }
        }
    }
}

// ---------------------------------------------------------------------------
// CSR build  [unchanged]
// ---------------------------------------------------------------------------
__global__ void hist_kernel(const int* __restrict__ n32, const int* __restrict__ flag,
                            int* __restrict__ counts)
{
    const int e = blockIdx.x * blockDim.x + threadIdx.x;
    const int str = flag[0] ? 4 : 2;
    if (e < N_EDGES) {
        const int d = n32[(size_t)str * e];
        atomicAdd(&counts[d], 1);
    }
}

__global__ __launch_bounds__(1024) void scan_kernel(const int* __restrict__ counts,
                                                    int* __restrict__ offsets,
                                                    int* __restrict__ cursor)
{
    __shared__ int sums[1024];
    const int t   = threadIdx.x;
    const int per = (N_NODES + 1023) / 1024;
    const int lo  = t * per;
    const int hi  = (lo + per < N_NODES) ? lo + per : N_NODES;
    int s = 0;
    for (int i = lo; i < hi; ++i) s += counts[i];
    sums[t] = s;
    __syncthreads();
    if (t == 0) {
        int run = 0;
        for (int i = 0; i < 1024; ++i) { const int v = sums[i]; sums[i] = run; run += v; }
        offsets[N_NODES] = run;
    }
    __syncthreads();
    int run = sums[t];
    for (int i = lo; i < hi; ++i) {
        offsets[i] = run;
        cursor[i]  = run;
        run += counts[i];
    }
}

__global__ void scatter_kernel(const int* __restrict__ n32, const int* __restrict__ flag,
                               int* __restrict__ cursor, int* __restrict__ csr)
{
    const int e = blockIdx.x * blockDim.x + threadIdx.x;
    const int str = flag[0] ? 4 : 2;
    if (e < N_EDGES) {
        const int d   = n32[(size_t)str * e];
        const int pos = atomicAdd(&cursor[d], 1);
        csr[pos] = e;
    }
}

// ---------------------------------------------------------------------------
// Kernel 5: per-node gather. One wave per node, Wd/bd in REGISTERS (84 VGPR,
// statically indexed), zero LDS, software-pipelined edge loop (prefetch next
// edge's indices + PHI row + r_ij during current edge's FMA chain).
// ---------------------------------------------------------------------------
__global__ __launch_bounds__(256, 3) void gather_kernel(
    const float* __restrict__ PHI, const float* __restrict__ r_ij,
    const int* __restrict__ n32, const int* __restrict__ flag,
    const float* __restrict__ Wd, const float* __restrict__ bd,
    const int* __restrict__ offsets, const int* __restrict__ csr,
    float* __restrict__ out_s, float* __restrict__ out_v)
{
    const int tid  = threadIdx.x;
    const int node = blockIdx.x * 4 + (tid >> 6);
    const int l    = tid & 63;
    if (node >= N_NODES) return;

    // lane l owns filter channels {l, l+64, l+128, l+192}
    float wd[NRBF][4];
    #pragma unroll
    for (int n = 0; n < NRBF; ++n) {
        wd[n][0] = Wd[n * 256 + l      ];
        wd[n][1] = Wd[n * 256 + l + 64 ];
        wd[n][2] = Wd[n * 256 + l + 128];
        wd[n][3] = Wd[n * 256 + l + 192];
    }
    const float bd0 = bd[l], bd1 = bd[l + 64], bd2 = bd[l + 128], bd3 = bd[l + 192];

    const int f64  = flag[0];
    const int str  = f64 ? 4 : 2;
    const int soff = f64 ? 2 : 1;

    const int beg = offsets[node];
    const int end = offsets[node + 1];

    float as0 = 0.f, as1 = 0.f;
    float av0x = 0.f, av0y = 0.f, av0z = 0.f;
    float av1x = 0.f, av1y = 0.f, av1z = 0.f;

    if (beg < end) {
        // prologue: load edge `beg`
        int e = __builtin_amdgcn_readfirstlane(csr[beg]);
        int j = __builtin_amdgcn_readfirstlane(n32[(size_t)str * e + soff]);
        const float* ph = PHI + (size_t)j * 256;
        float p0 = ph[l], p1 = ph[l + 64], p2 = ph[l + 128], p3 = ph[l + 192];
        float rx = r_ij[3 * (size_t)e + 0];
        float ry = r_ij[3 * (size_t)e + 1];
        float rz = r_ij[3 * (size_t)e + 2];

        for (int p = beg; p < end; ++p) {
            // ---- prefetch edge p+1 (clamped; overlaps the FMA chain below) ----
            const int pn = (p + 1 < end) ? (p + 1) : p;
            const int e2 = __builtin_amdgcn_readfirstlane(csr[pn]);
            const int j2 = __builtin_amdgcn_readfirstlane(n32[(size_t)str * e2 + soff]);
            const float* ph2 = PHI + (size_t)j2 * 256;
            const float q0 = ph2[l], q1 = ph2[l + 64], q2 = ph2[l + 128], q3 = ph2[l + 192];
            const float sx = r_ij[3 * (size_t)e2 + 0];
            const float sy = r_ij[3 * (size_t)e2 + 1];
            const float sz = r_ij[3 * (size_t)e2 + 2];

            // ---- compute current edge ----
            const float d2    = fmaf(rx, rx, fmaf(ry, ry, fmaf(rz, rz, 3e-8f)));
            const float inv_d = __frsqrt_rn(d2);          // v_rsq_f32
            const float dist  = d2 * inv_d;
            const float x  = (PI_F / CUTOFF_R) * dist;
            const float sn = __sinf(x);
            const float cn = __cosf(x);
            const float env  = (dist < CUTOFF_R) ? (0.5f * (cn + 1.0f)) : 0.0f;
            const float twoc = cn + cn;

            // w_s = rbf @ Wd + bd  (Chebyshev: sin((n+1)x)=2cos(x)sin(nx)-sin((n-1)x))
            float w0 = bd0, w1 = bd1, w2 = bd2, w3 = bd3;
            float sm1 = 0.f, scur = sn;
            #pragma unroll
            for (int n = 0; n < NRBF; ++n) {
                const float rb = scur * inv_d;
                w0 = fmaf(rb, wd[n][0], w0);
                w1 = fmaf(rb, wd[n][1], w1);
                w2 = fmaf(rb, wd[n][2], w2);
                w3 = fmaf(rb, wd[n][3], w3);
                const float nxt = fmaf(twoc, scur, -sm1);
                sm1 = scur; scur = nxt;
            }

            const float ux = rx * inv_d, uy = ry * inv_d, uz = rz * inv_d;
            const float e0 = p0 * (w0 * env);
            const float e1 = p1 * (w1 * env);
            as0 = fmaf(p2, w2 * env, as0);
            as1 = fmaf(p3, w3 * env, as1);
            av0x = fmaf(e0, ux, av0x); av0y = fmaf(e0, uy, av0y); av0z = fmaf(e0, uz, av0z);
            av1x = fmaf(e1, ux, av1x); av1y = fmaf(e1, uy, av1y); av1z = fmaf(e1, uz, av1z);

            // ---- shift pipeline ----
            p0 = q0; p1 = q1; p2 = q2; p3 = q3;
            rx = sx; ry = sy; rz = sz;
        }
    }

    out_s[(size_t)node * FDIM + l]      = as0;
    out_s[(size_t)node * FDIM + 64 + l] = as1;
    const size_t vb0 = ((size_t)node * FDIM + l) * 3;
    const size_t vb1 = ((size_t)node * FDIM + 64 + l) * 3;
    out_v[vb0 + 0] = av0x; out_v[vb0 + 1] = av0y; out_v[vb0 + 2] = av0z;
    out_v[vb1 + 0] = av1x; out_v[vb1 + 1] = av1y; out_v[vb1 + 2] = av1z;
}

// ---------------------------------------------------------------------------
extern "C" void kernel_launch(void* const* d_in, const int* in_sizes, int n_in,
                              void* d_out, int out_size, void* d_ws, size_t ws_size,
                              hipStream_t stream)
{
    (void)in_sizes; (void)n_in; (void)out_size; (void)ws_size;
    const float* s_j  = (const float*)d_in[0];
    // d_in[1] = v_j : UNUSED by the reference computation — never read
    const float* r_ij = (const float*)d_in[2];
    const int*   n32  = (const int*)d_in[3];
    const float* W1   = (const float*)d_in[4];
    const float* b1   = (const float*)d_in[5];
    const float* W2   = (const float*)d_in[6];
    const float* b2   = (const float*)d_in[7];
    const float* Wd   = (const float*)d_in[8];
    const float* bd   = (const float*)d_in[9];

    float* out_s = (float*)d_out;
    float* out_v = out_s + (size_t)N_NODES * FDIM;

    char*  ws      = (char*)d_ws;
    float* PHI     = (float*)(ws);                 // N*256 f32 = 51.2 MB
    int*   counts  = (int*)(ws + 51200000);
    int*   offsets = (int*)(ws + 51400000);
    int*   cursor  = (int*)(ws + 51600128);
    int*   csr     = (int*)(ws + 51800128);
    int*   flag    = (int*)(ws + 55000128);

    hipMemsetAsync(counts, 0, N_NODES * sizeof(int), stream);

    detect_kernel <<<1, 256, 0, stream>>>(n32, flag);
    node_mlp_kernel<<<(N_NODES + 63) / 64, 256, 0, stream>>>(s_j, W1, b1, W2, b2, PHI);
    hist_kernel   <<<(N_EDGES + 255) / 256, 256, 0, stream>>>(n32, flag, counts);
    scan_kernel   <<<1, 1024, 0, stream>>>(counts, offsets, cursor);
    scatter_kernel<<<(N_EDGES + 255) / 256, 256, 0, stream>>>(n32, flag, cursor, csr);
    gather_kernel <<<(N_NODES + 3) / 4, 256, 0, stream>>>(PHI, r_ij, n32, flag, Wd, bd,
                                                          offsets, csr, out_s, out_v);
}

// Round 6
// 676.453 us; speedup vs baseline: 1.3149x; 1.0570x over previous
//
#include <hip/hip_runtime.h>
#include <hip/hip_bf16.h>
#include <cstdint>
#include <cstddef>

#define N_NODES 50000
#define N_EDGES 800000
#define FDIM    128
#define NRBF    20
#define CUTOFF_R 5.0f
#define PI_F 3.14159265358979323846f

// ---------------------------------------------------------------------------
// Kernel 0: detect nbrs dtype (int64 vs int32 demotion). flag=1 -> int64.
// ---------------------------------------------------------------------------
__global__ void detect_kernel(const int* __restrict__ n32, int* __restrict__ flag)
{
    __shared__ int any;
    if (threadIdx.x == 0) any = 0;
    __syncthreads();
    int nz = 0;
    for (int k = threadIdx.x; k < 1024; k += 256)
        nz |= (n32[2 * k + 1] != 0) ? 1 : 0;
    if (nz) atomicOr(&any, 1);
    __syncthreads();
    if (threadIdx.x == 0) flag[0] = any ? 0 : 1;
}

// ---------------------------------------------------------------------------
// Kernel 1: PHI = silu(S @ W1 + b1) @ W2 + b2   (N x 256)
// 64-row tile, 256 threads. Thread (ty=tid>>4, tx=tid&15) owns rows ty*4+i,
// cols tx*4 + 64*h. b-reads are float4 at stride-64 offsets -> bank pattern
// tx*4 (2-way alias = free); a-reads are 2-way broadcasts. BK1=32, BK2=16.
// LDS = 64*132*4 + 4096*4 = 50 KB -> 3 blocks/CU.
// ---------------------------------------------------------------------------
__global__ __launch_bounds__(256) void node_mlp_kernel(
    const float* __restrict__ S,  const float* __restrict__ W1, const float* __restrict__ b1,
    const float* __restrict__ W2, const float* __restrict__ b2, float* __restrict__ PHI)
{
    __shared__ float sS[64][132];   // S tile, later overwritten with H (own rows only)
    __shared__ float sW[4096];

    const int tid  = threadIdx.x;
    const int row0 = blockIdx.x * 64;
    const int ty   = tid >> 4;      // 0..15
    const int tx   = tid & 15;      // 0..15

    // stage S tile (64 x 128), clamp OOB rows
    for (int i = tid; i < 2048; i += 256) {
        const int r  = i >> 5;
        const int c4 = (i & 31) * 4;
        int gr = row0 + r; if (gr >= N_NODES) gr = N_NODES - 1;
        *reinterpret_cast<float4*>(&sS[r][c4]) =
            *reinterpret_cast<const float4*>(&S[(size_t)gr * FDIM + c4]);
    }

    // ---- phase 1: H = silu(S@W1 + b1) ----
    float acc1[4][8];
    #pragma unroll
    for (int i = 0; i < 4; ++i)
        #pragma unroll
        for (int j = 0; j < 8; ++j) acc1[i][j] = 0.f;

    for (int kk = 0; kk < 128; kk += 32) {
        __syncthreads();
        // stage W1 rows [kk..kk+32) x 128
        for (int i = tid; i < 1024; i += 256) {
            const int r  = i >> 5;
            const int c4 = (i & 31) * 4;
            *reinterpret_cast<float4*>(&sW[r * 128 + c4]) =
                *reinterpret_cast<const float4*>(&W1[(size_t)(kk + r) * 128 + c4]);
        }
        __syncthreads();
        #pragma unroll
        for (int k2 = 0; k2 < 32; ++k2) {
            float a[4];
            #pragma unroll
            for (int i = 0; i < 4; ++i) a[i] = sS[ty * 4 + i][kk + k2];
            const float4 b0 = *reinterpret_cast<const float4*>(&sW[k2 * 128 + tx * 4]);
            const float4 b4 = *reinterpret_cast<const float4*>(&sW[k2 * 128 + 64 + tx * 4]);
            const float bb[8] = {b0.x, b0.y, b0.z, b0.w, b4.x, b4.y, b4.z, b4.w};
            #pragma unroll
            for (int i = 0; i < 4; ++i)
                #pragma unroll
                for (int j = 0; j < 8; ++j) acc1[i][j] = fmaf(a[i], bb[j], acc1[i][j]);
        }
    }
    {
        const float4 c0 = *reinterpret_cast<const float4*>(&b1[tx * 4]);
        const float4 c4 = *reinterpret_cast<const float4*>(&b1[64 + tx * 4]);
        const float bb[8] = {c0.x, c0.y, c0.z, c0.w, c4.x, c4.y, c4.z, c4.w};
        #pragma unroll
        for (int i = 0; i < 4; ++i) {
            #pragma unroll
            for (int j = 0; j < 8; ++j) {
                const int c = (j < 4) ? (tx * 4 + j) : (64 + tx * 4 + (j - 4));
                const float x = acc1[i][j] + bb[j];
                sS[ty * 4 + i][c] = x / (1.f + __expf(-x));   // silu, in place (own rows)
            }
        }
    }

    // ---- phase 2: PHI = H@W2 + b2 (256 cols: tx*4 + 64h, h=0..3) ----
    float acc2[4][16];
    #pragma unroll
    for (int i = 0; i < 4; ++i)
        #pragma unroll
        for (int j = 0; j < 16; ++j) acc2[i][j] = 0.f;

    for (int kk = 0; kk < 128; kk += 16) {
        __syncthreads();   // fences in-place H writes (first iter) + sW reuse
        // stage W2 rows [kk..kk+16) x 256
        for (int i = tid; i < 1024; i += 256) {
            const int r  = i >> 6;
            const int c4 = (i & 63) * 4;
            *reinterpret_cast<float4*>(&sW[r * 256 + c4]) =
                *reinterpret_cast<const float4*>(&W2[(size_t)(kk + r) * 256 + c4]);
        }
        __syncthreads();
        #pragma unroll
        for (int k2 = 0; k2 < 16; ++k2) {
            float a[4];
            #pragma unroll
            for (int i = 0; i < 4; ++i) a[i] = sS[ty * 4 + i][kk + k2];
            #pragma unroll
            for (int h = 0; h < 4; ++h) {
                const float4 b = *reinterpret_cast<const float4*>(&sW[k2 * 256 + h * 64 + tx * 4]);
                const float bb[4] = {b.x, b.y, b.z, b.w};
                #pragma unroll
                for (int i = 0; i < 4; ++i)
                    #pragma unroll
                    for (int j = 0; j < 4; ++j)
                        acc2[i][h * 4 + j] = fmaf(a[i], bb[j], acc2[i][h * 4 + j]);
            }
        }
    }
    #pragma unroll
    for (int i = 0; i < 4; ++i) {
        const int gr = row0 + ty * 4 + i;
        if (gr < N_NODES) {
            #pragma unroll
            for (int h = 0; h < 4; ++h) {
                const float4 c = *reinterpret_cast<const float4*>(&b2[h * 64 + tx * 4]);
                float4 o;
                o.x = acc2[i][h * 4 + 0] + c.x;
                o.y = acc2[i][h * 4 + 1] + c.y;
                o.z = acc2[i][h * 4 + 2] + c.z;
                o.w = acc2[i][h * 4 + 3] + c.w;
                *reinterpret_cast<float4*>(&PHI[(size_t)gr * 256 + h * 64 + tx * 4]) = o;
            }
        }
    }
}

// ---------------------------------------------------------------------------
// CSR build
// ---------------------------------------------------------------------------
__global__ void hist_kernel(const int* __restrict__ n32, const int* __restrict__ flag,
                            int* __restrict__ counts)
{
    const int e = blockIdx.x * blockDim.x + threadIdx.x;
    const int str = flag[0] ? 4 : 2;
    if (e < N_EDGES) {
        const int d = n32[(size_t)str * e];
        atomicAdd(&counts[d], 1);
    }
}

// wave-parallel scan (replaces thread0-serial-1024 version)
__global__ __launch_bounds__(1024) void scan_kernel(const int* __restrict__ counts,
                                                    int* __restrict__ offsets,
                                                    int* __restrict__ cursor)
{
    __shared__ int wsum[16];
    const int t    = threadIdx.x;
    const int lane = t & 63;
    const int wid  = t >> 6;
    const int per  = (N_NODES + 1023) / 1024;   // 49
    const int lo   = t * per;
    const int hi   = (lo + per < N_NODES) ? lo + per : N_NODES;

    int s = 0;
    for (int i = lo; i < hi; ++i) s += counts[i];

    // inclusive scan within wave
    int inc = s;
    #pragma unroll
    for (int off = 1; off < 64; off <<= 1) {
        const int v = __shfl_up(inc, off, 64);
        if (lane >= off) inc += v;
    }
    if (lane == 63) wsum[wid] = inc;
    __syncthreads();
    if (t == 0) {
        int run = 0;
        #pragma unroll
        for (int i = 0; i < 16; ++i) { const int v = wsum[i]; wsum[i] = run; run += v; }
        offsets[N_NODES] = run;   // == N_EDGES
    }
    __syncthreads();

    int run = wsum[wid] + inc - s;   // exclusive prefix for this thread
    for (int i = lo; i < hi; ++i) {
        offsets[i] = run;
        cursor[i]  = run;
        run += counts[i];
    }
}

__global__ void scatter_kernel(const int* __restrict__ n32, const int* __restrict__ flag,
                               int* __restrict__ cursor, int* __restrict__ csr)
{
    const int e = blockIdx.x * blockDim.x + threadIdx.x;
    const int str = flag[0] ? 4 : 2;
    if (e < N_EDGES) {
        const int d   = n32[(size_t)str * e];
        const int pos = atomicAdd(&cursor[d], 1);
        csr[pos] = e;
    }
}

// ---------------------------------------------------------------------------
// Kernel 5: per-node gather. Wd/bd pinned in VGPRs via asm reg-barrier
// (prevents the compiler from sinking the loads back into the edge loop,
// which is what happened with the plain array: VGPR_Count was only 60).
// Software-pipelined edge loop (depth 1).
// ---------------------------------------------------------------------------
__global__ __launch_bounds__(256) void gather_kernel(
    const float* __restrict__ PHI, const float* __restrict__ r_ij,
    const int* __restrict__ n32, const int* __restrict__ flag,
    const float* __restrict__ Wd, const float* __restrict__ bd,
    const int* __restrict__ offsets, const int* __restrict__ csr,
    float* __restrict__ out_s, float* __restrict__ out_v)
{
    const int tid  = threadIdx.x;
    const int node = blockIdx.x * 4 + (tid >> 6);
    const int l    = tid & 63;
    if (node >= N_NODES) return;

    // lane l owns filter channels {l, l+64, l+128, l+192}
    float wd0[NRBF], wd1[NRBF], wd2[NRBF], wd3[NRBF];
    #pragma unroll
    for (int n = 0; n < NRBF; ++n) {
        wd0[n] = Wd[n * 256 + l      ];
        wd1[n] = Wd[n * 256 + l + 64 ];
        wd2[n] = Wd[n * 256 + l + 128];
        wd3[n] = Wd[n * 256 + l + 192];
    }
    // pin in registers: asm output is opaque -> cannot be rematerialized from memory
    #pragma unroll
    for (int n = 0; n < NRBF; ++n) {
        asm volatile("" : "+v"(wd0[n]), "+v"(wd1[n]), "+v"(wd2[n]), "+v"(wd3[n]));
    }
    const float bd0 = bd[l], bd1 = bd[l + 64], bd2 = bd[l + 128], bd3 = bd[l + 192];

    const int f64  = flag[0];
    const int str  = f64 ? 4 : 2;
    const int soff = f64 ? 2 : 1;

    const int beg = offsets[node];
    const int end = offsets[node + 1];

    float as0 = 0.f, as1 = 0.f;
    float av0x = 0.f, av0y = 0.f, av0z = 0.f;
    float av1x = 0.f, av1y = 0.f, av1z = 0.f;

    if (beg < end) {
        int e = __builtin_amdgcn_readfirstlane(csr[beg]);
        int j = __builtin_amdgcn_readfirstlane(n32[(size_t)str * e + soff]);
        const float* ph = PHI + (size_t)j * 256;
        float p0 = ph[l], p1 = ph[l + 64], p2 = ph[l + 128], p3 = ph[l + 192];
        float rx = r_ij[3 * (size_t)e + 0];
        float ry = r_ij[3 * (size_t)e + 1];
        float rz = r_ij[3 * (size_t)e + 2];

        for (int p = beg; p < end; ++p) {
            // ---- prefetch edge p+1 (clamped) ----
            const int pn = (p + 1 < end) ? (p + 1) : p;
            const int e2 = __builtin_amdgcn_readfirstlane(csr[pn]);
            const int j2 = __builtin_amdgcn_readfirstlane(n32[(size_t)str * e2 + soff]);
            const float* ph2 = PHI + (size_t)j2 * 256;
            const float q0 = ph2[l], q1 = ph2[l + 64], q2 = ph2[l + 128], q3 = ph2[l + 192];
            const float sx = r_ij[3 * (size_t)e2 + 0];
            const float sy = r_ij[3 * (size_t)e2 + 1];
            const float sz = r_ij[3 * (size_t)e2 + 2];

            // ---- compute current edge ----
            const float d2    = fmaf(rx, rx, fmaf(ry, ry, fmaf(rz, rz, 3e-8f)));
            const float inv_d = __frsqrt_rn(d2);
            const float dist  = d2 * inv_d;
            const float x  = (PI_F / CUTOFF_R) * dist;
            const float sn = __sinf(x);
            const float cn = __cosf(x);
            const float env  = (dist < CUTOFF_R) ? (0.5f * (cn + 1.0f)) : 0.0f;
            const float twoc = cn + cn;

            float w0 = bd0, w1 = bd1, w2 = bd2, w3 = bd3;
            float sm1 = 0.f, scur = sn;
            #pragma unroll
            for (int n = 0; n < NRBF; ++n) {
                const float rb = scur * inv_d;
                w0 = fmaf(rb, wd0[n], w0);
                w1 = fmaf(rb, wd1[n], w1);
                w2 = fmaf(rb, wd2[n], w2);
                w3 = fmaf(rb, wd3[n], w3);
                const float nxt = fmaf(twoc, scur, -sm1);
                sm1 = scur; scur = nxt;
            }

            const float ux = rx * inv_d, uy = ry * inv_d, uz = rz * inv_d;
            const float e0 = p0 * (w0 * env);
            const float e1 = p1 * (w1 * env);
            as0 = fmaf(p2, w2 * env, as0);
            as1 = fmaf(p3, w3 * env, as1);
            av0x = fmaf(e0, ux, av0x); av0y = fmaf(e0, uy, av0y); av0z = fmaf(e0, uz, av0z);
            av1x = fmaf(e1, ux, av1x); av1y = fmaf(e1, uy, av1y); av1z = fmaf(e1, uz, av1z);

            p0 = q0; p1 = q1; p2 = q2; p3 = q3;
            rx = sx; ry = sy; rz = sz;
        }
    }

    out_s[(size_t)node * FDIM + l]      = as0;
    out_s[(size_t)node * FDIM + 64 + l] = as1;
    const size_t vb0 = ((size_t)node * FDIM + l) * 3;
    const size_t vb1 = ((size_t)node * FDIM + 64 + l) * 3;
    out_v[vb0 + 0] = av0x; out_v[vb0 + 1] = av0y; out_v[vb0 + 2] = av0z;
    out_v[vb1 + 0] = av1x; out_v[vb1 + 1] = av1y; out_v[vb1 + 2] = av1z;
}

// ---------------------------------------------------------------------------
extern "C" void kernel_launch(void* const* d_in, const int* in_sizes, int n_in,
                              void* d_out, int out_size, void* d_ws, size_t ws_size,
                              hipStream_t stream)
{
    (void)in_sizes; (void)n_in; (void)out_size; (void)ws_size;
    const float* s_j  = (const float*)d_in[0];
    // d_in[1] = v_j : UNUSED by the reference computation — never read
    const float* r_ij = (const float*)d_in[2];
    const int*   n32  = (const int*)d_in[3];
    const float* W1   = (const float*)d_in[4];
    const float* b1   = (const float*)d_in[5];
    const float* W2   = (const float*)d_in[6];
    const float* b2   = (const float*)d_in[7];
    const float* Wd   = (const float*)d_in[8];
    const float* bd   = (const float*)d_in[9];

    float* out_s = (float*)d_out;
    float* out_v = out_s + (size_t)N_NODES * FDIM;

    char*  ws      = (char*)d_ws;
    float* PHI     = (float*)(ws);                 // N*256 f32 = 51.2 MB
    int*   counts  = (int*)(ws + 51200000);
    int*   offsets = (int*)(ws + 51400000);
    int*   cursor  = (int*)(ws + 51600128);
    int*   csr     = (int*)(ws + 51800128);
    int*   flag    = (int*)(ws + 55000128);

    hipMemsetAsync(counts, 0, N_NODES * sizeof(int), stream);

    detect_kernel <<<1, 256, 0, stream>>>(n32, flag);
    node_mlp_kernel<<<(N_NODES + 63) / 64, 256, 0, stream>>>(s_j, W1, b1, W2, b2, PHI);
    hist_kernel   <<<(N_EDGES + 255) / 256, 256, 0, stream>>>(n32, flag, counts);
    scan_kernel   <<<1, 1024, 0, stream>>>(counts, offsets, cursor);
    scatter_kernel<<<(N_EDGES + 255) / 256, 256, 0, stream>>>(n32, flag, cursor, csr);
    gather_kernel <<<(N_NODES + 3) / 4, 256, 0, stream>>>(PHI, r_ij, n32, flag, Wd, bd,
                                                          offsets, csr, out_s, out_v);
}